// Round 1
// baseline (6664.659 us; speedup 1.0000x reference)
//
#include <hip/hip_runtime.h>
#include <stdint.h>

#define NPIX 65536      // 256*256
#define NRE  65280      // right edges: 256 rows * 255
#define NE   130560     // total edges (right + down)
#define NIMG 4
#define TPB  1024

// decode implicit grid edge -> original pixel endpoints (row-major 256x256)
__device__ __forceinline__ void edge_uv(int e, int& u, int& v){
  if (e < NRE){ int r = e / 255; int c = e - r*255; u = (r<<8) + c; v = u + 1; }
  else        { u = e - NRE; v = u + 256; }
}

// union-find with path compression; roots are stable within a phase, so
// concurrent compression writes all store the same final root (benign).
__device__ __forceinline__ int find_root(unsigned int* lbl, int x){
  int r = x;
  int c = (int)lbl[r];
  while (c != r){ r = c; c = (int)lbl[r]; }
  while ((int)lbl[x] != r){ int nxt = (int)lbl[x]; lbl[x] = (unsigned)r; x = nxt; }
  return r;
}

__global__ __launch_bounds__(TPB)
void ph0_kernel(const float* __restrict__ prob, const float* __restrict__ roi,
                unsigned long long* __restrict__ ME, float* __restrict__ F,
                float* __restrict__ LIFE, unsigned int* __restrict__ LBL,
                ushort2* __restrict__ AB, float* __restrict__ LOSS)
{
  const int img = blockIdx.x;
  const int tid = threadIdx.x;
  const float* __restrict__ pm = prob + (size_t)img*NPIX;
  const float* __restrict__ rm = roi  + (size_t)img*NPIX;
  unsigned long long* me = ME + (size_t)img*NPIX;
  float* f    = F    + (size_t)img*NPIX;
  float* life = LIFE + (size_t)img*NPIX;
  unsigned int* lbl = LBL + (size_t)img*NPIX;
  ushort2* ab = AB + (size_t)img*NE;

  __shared__ int   s_cnt;
  __shared__ float s_val[TPB];
  __shared__ int   s_idx[TPB];
  __shared__ int   s_sel[5];

  // ---- init: filtration f = 1 - prob*roi, lifetimes 0, singleton labels ----
  for (int i = tid; i < NPIX; i += TPB){
    float pr = pm[i] * rm[i];
    f[i] = 1.0f - pr;          // f in (0,1]; float bits are monotone keys
    life[i] = 0.0f;
    lbl[i] = (unsigned)i;
  }
  for (int e = tid; e < NE; e += TPB){
    int u,v; edge_uv(e,u,v);
    ab[e] = make_ushort2((unsigned short)u, (unsigned short)v);
  }
  __syncthreads();

  // ---- rounds: parallel elder-rule contraction ----
  for (int round = 0; round < 70000; ++round){
    for (int i = tid; i < NPIX; i += TPB) me[i] = ~0ULL;
    if (tid == 0) s_cnt = 0;
    __syncthreads();

    // phase 1: relabel edges to current roots, per-root min edge key
    for (int e = tid; e < NE; e += TPB){
      ushort2 q = ab[e];
      int a = q.x, b = q.y;
      if (a == b) continue;                      // dead edge
      a = find_root(lbl, a);
      b = find_root(lbl, b);
      ab[e] = make_ushort2((unsigned short)a, (unsigned short)b);
      if (a == b) continue;
      int u,v; edge_uv(e,u,v);
      float w = fmaxf(f[u], f[v]);               // fixed edge weight
      unsigned long long key =
          ((unsigned long long)__float_as_uint(w) << 17) | (unsigned)e; // unique
      atomicMin(&me[a], key);
      atomicMin(&me[b], key);
    }
    __syncthreads();

    // phase 2: fire — a root dies via its min edge iff the opposite
    // round-start root is strictly deeper (lex (f, idx)). Exact pairing.
    int local = 0;
    for (int e = tid; e < NE; e += TPB){
      ushort2 q = ab[e];
      int a = q.x, b = q.y;
      if (a == b) continue;
      int u,v; edge_uv(e,u,v);
      float w = fmaxf(f[u], f[v]);
      unsigned long long key =
          ((unsigned long long)__float_as_uint(w) << 17) | (unsigned)e;
      float fa = f[a], fb = f[b];
      bool b_deeper = (fb < fa) || ((fb == fa) && (b < a));
      if (me[a] == key && b_deeper){  life[a] = w - fa; lbl[a] = (unsigned)b; ++local; }
      if (me[b] == key && !b_deeper){ life[b] = w - fb; lbl[b] = (unsigned)a; ++local; }
    }
    if (local) atomicAdd(&s_cnt, local);
    __syncthreads();
    int total = s_cnt;
    __syncthreads();                              // reads done before next reset
    if (total == 0) break;                        // uniform exit
  }

  // ---- top-5 lifetimes -> per-image loss ----
  float lsum = 0.0f;
  for (int k = 0; k < 5; ++k){
    float bv = -1.0f; int bi = NPIX;
    for (int i = tid; i < NPIX; i += TPB){
      bool skip = false;
      #pragma unroll
      for (int j = 0; j < 5; ++j) if (j < k && s_sel[j] == i) skip = true;
      if (!skip){
        float v = life[i];
        if (v > bv){ bv = v; bi = i; }
      }
    }
    s_val[tid] = bv; s_idx[tid] = bi;
    __syncthreads();
    for (int off = TPB>>1; off > 0; off >>= 1){
      if (tid < off){
        float ov = s_val[tid+off];
        if (ov > s_val[tid]){ s_val[tid] = ov; s_idx[tid] = s_idx[tid+off]; }
      }
      __syncthreads();
    }
    if (tid == 0) s_sel[k] = s_idx[0];
    float d = s_val[0] - 0.5f;                    // TARGET_LIFETIME
    lsum += d*d;
    __syncthreads();
  }
  if (tid == 0) LOSS[img] = lsum * 0.2f;          // / n_use (=5 always)
}

__global__ void finalize_kernel(const float* __restrict__ LOSS, float* __restrict__ out){
  // mean over 4 images * LOSS_SCALE(100) = sum * 25
  out[0] = (LOSS[0]+LOSS[1]+LOSS[2]+LOSS[3]) * 25.0f;
}

extern "C" void kernel_launch(void* const* d_in, const int* in_sizes, int n_in,
                              void* d_out, int out_size, void* d_ws, size_t ws_size,
                              hipStream_t stream)
{
  const float* prob = (const float*)d_in[0];
  const float* roi  = (const float*)d_in[1];
  char* ws = (char*)d_ws;
  // layout (8B-aligned first): ME 2MB | F 1MB | LIFE 1MB | LBL 1MB | AB ~2MB | LOSS
  unsigned long long* ME = (unsigned long long*)ws;
  float*        F    = (float*)(ws + 2097152);
  float*        LIFE = (float*)(ws + 2097152 + 1048576);
  unsigned int* LBL  = (unsigned int*)(ws + 2097152 + 2*1048576);
  ushort2*      AB   = (ushort2*)(ws + 2097152 + 3*1048576);
  float*        LOSS = (float*)(ws + 2097152 + 3*1048576 + 2088960);

  ph0_kernel<<<NIMG, TPB, 0, stream>>>(prob, roi, ME, F, LIFE, LBL, AB, LOSS);
  finalize_kernel<<<1, 1, 0, stream>>>(LOSS, (float*)d_out);
}

// Round 2
// 924.317 us; speedup vs baseline: 7.2104x; 7.2104x over previous
//
#include <hip/hip_runtime.h>
#include <hip/hip_cooperative_groups.h>
#include <stdint.h>

namespace cg = cooperative_groups;

#define NPIX 65536      // 256*256
#define NRE  65280      // right edges: 256 rows * 255
#define NE   130560     // total edges
#define NIMG 4
#define TPB  512
#define BPI  16                 // blocks per image
#define NBLK (NIMG*BPI)         // 64 blocks
#define NT   (BPI*TPB)          // threads per image
#define MAXR 8192
#define THRESH 8192
#define MASK48 0xFFFFFFFFFFFFULL

__device__ __forceinline__ void edge_uv(int e, int& u, int& v){
  if (e < NRE){ int r = e / 255; int c = e - r*255; u = (r<<8) + c; v = u + 1; }
  else        { u = e - NRE; v = u + 256; }
}

// roots are stable within a phase; concurrent compression writes are benign
__device__ __forceinline__ int find_root(unsigned int* lbl, int x){
  int r = x, c = (int)lbl[r];
  while (c != r){ r = c; c = (int)lbl[r]; }
  while ((int)lbl[x] != r){ int nxt = (int)lbl[x]; lbl[x] = (unsigned)r; x = nxt; }
  return r;
}

__global__ __launch_bounds__(TPB)
void ph0_coop(const float* __restrict__ prob, const float* __restrict__ roi,
              float* __restrict__ Fg, float* __restrict__ LIFEg,
              unsigned int* __restrict__ LBLg, unsigned long long* __restrict__ MEg,
              unsigned long long* __restrict__ LAg, unsigned long long* __restrict__ LBg,
              unsigned int* __restrict__ C, float* __restrict__ LOSS)
{
  cg::grid_group grid = cg::this_grid();
  const int img = blockIdx.x / BPI;
  const int lb  = blockIdx.x - img*BPI;
  const int tid = threadIdx.x;
  const int lt  = lb*TPB + tid;
  const int lane = tid & 63;

  float* f    = Fg    + img*NPIX;
  float* life = LIFEg + img*NPIX;
  unsigned int* lbl = LBLg + img*NPIX;
  unsigned long long* me = MEg + img*NPIX;
  unsigned long long* lists[2] = { LAg + (size_t)img*NE, LBg + (size_t)img*NE };
  const float* pm = prob + img*NPIX;
  const float* rm = roi  + img*NPIX;

  __shared__ int   s_n;
  __shared__ float cand[TPB*5];
  __shared__ float s_val[TPB];
  __shared__ int   s_idx[TPB];

  // ---- init ----
  for (int i = lt; i < NPIX; i += NT){
    f[i] = 1.0f - pm[i]*rm[i];
    life[i] = 0.0f;
    lbl[i] = (unsigned)i;
    me[i] = 0ULL;                         // any tagged value (round>=1) beats 0
  }
  {
    int gt = blockIdx.x*TPB + tid;
    if (gt < 2*NIMG) C[gt] = 0;
  }
  grid.sync();

  // ---- round -1: every pixel is a root; fire directly against min incident edge ----
  for (int i = lt; i < NPIX; i += NT){
    int r = i >> 8, c = i & 255;
    float fi = f[i];
    unsigned long long best = ~0ULL; int bj = 0; float bw = 0.0f;
    if (c > 0){
      float w = fmaxf(f[i-1], fi);
      unsigned long long k = ((unsigned long long)__float_as_uint(w)<<17) | (unsigned)(r*255 + c - 1);
      if (k < best){ best = k; bj = i-1; bw = w; }
    }
    if (c < 255){
      float w = fmaxf(f[i+1], fi);
      unsigned long long k = ((unsigned long long)__float_as_uint(w)<<17) | (unsigned)(r*255 + c);
      if (k < best){ best = k; bj = i+1; bw = w; }
    }
    if (r > 0){
      float w = fmaxf(f[i-256], fi);
      unsigned long long k = ((unsigned long long)__float_as_uint(w)<<17) | (unsigned)(NRE + (r-1)*256 + c);
      if (k < best){ best = k; bj = i-256; bw = w; }
    }
    if (r < 255){
      float w = fmaxf(f[i+256], fi);
      unsigned long long k = ((unsigned long long)__float_as_uint(w)<<17) | (unsigned)(NRE + r*256 + c);
      if (k < best){ best = k; bj = i+256; bw = w; }
    }
    float fj = f[bj];
    if ((fj < fi) || ((fj == fi) && (bj < i))){   // opposite singleton root deeper
      life[i] = bw - fi;
      lbl[i] = (unsigned)bj;
    }
  }
  grid.sync();

  // ---- rounds over compacted survivor lists ----
  int p = 0, n_prev = -1, roundIdx = 1, solo = 0;

  for (;;){
    unsigned long long tag = (unsigned long long)roundIdx << 48;
    unsigned long long* cur = lists[p];
    unsigned long long* src = lists[1-p];
    unsigned int* ctr = &C[p*NIMG + img];
    int M = (n_prev < 0) ? NE : n_prev;
    int Mpad = (M + 63) & ~63;

    if (solo){ if (tid == 0) s_n = 0; __syncthreads(); }
    const int my_lt = solo ? tid : lt;
    const int my_nt = solo ? TPB : NT;

    // phase 1: relabel -> compact survivors -> per-root min key (round-tagged atomicMax)
    for (int idx = my_lt; idx < Mpad; idx += my_nt){
      bool keep = false;
      int e = 0, a = 0, b = 0;
      if (idx < M){
        if (n_prev < 0){ e = idx; edge_uv(e, a, b); }
        else {
          unsigned long long ent = src[idx];
          e = (int)(ent & 0xFFFFFFFFu);
          a = (int)((ent >> 32) & 0xFFFF);
          b = (int)(ent >> 48);
        }
        a = find_root(lbl, a);
        b = find_root(lbl, b);
        keep = (a != b);
      }
      unsigned long long m = __ballot(keep);
      if (m){
        int pos = __popcll(m & ((1ULL<<lane) - 1));
        int leader = __ffsll((long long)m) - 1;
        int base = 0;
        if (lane == leader){
          int cnt = __popcll(m);
          base = solo ? atomicAdd(&s_n, cnt) : (int)atomicAdd(ctr, (unsigned)cnt);
        }
        base = __shfl(base, leader);
        if (keep){
          int u, v; edge_uv(e, u, v);
          float w = fmaxf(f[u], f[v]);
          unsigned long long kl = ((unsigned long long)__float_as_uint(w)<<17) | (unsigned)e;
          unsigned long long val = tag | (MASK48 - kl);
          atomicMax(&me[a], val);
          atomicMax(&me[b], val);
          cur[base + pos] = ((unsigned long long)(unsigned)b << 48) |
                            ((unsigned long long)(unsigned)a << 32) | (unsigned)e;
        }
      }
    }

    int n_new, total_active;
    if (solo){
      __syncthreads();
      n_new = s_n;
      total_active = n_new;
    } else {
      grid.sync();
      n_new = (int)C[p*NIMG + img];
      total_active = (int)C[p*NIMG+0] + (int)C[p*NIMG+1] + (int)C[p*NIMG+2] + (int)C[p*NIMG+3];
      if (total_active <= THRESH){
        if (lb != 0) return;            // non-leaders retire; no grid.sync beyond this point
        solo = 1;
      }
      if (lb == 0 && tid == 0) C[(1-p)*NIMG + img] = 0;   // ping-pong reset for next round
    }
    if (total_active == 0) break;       // nonempty list always produces >=1 fire

    // phase 2: fire — root dies via its min edge iff opposite round-start root deeper
    for (int idx = my_lt; idx < n_new; idx += my_nt){
      unsigned long long ent = cur[idx];
      int e = (int)(ent & 0xFFFFFFFFu);
      int a = (int)((ent >> 32) & 0xFFFF);
      int b = (int)(ent >> 48);
      int u, v; edge_uv(e, u, v);
      float w = fmaxf(f[u], f[v]);
      unsigned long long kl = ((unsigned long long)__float_as_uint(w)<<17) | (unsigned)e;
      unsigned long long val = tag | (MASK48 - kl);
      float fa = f[a], fb = f[b];
      bool bd = (fb < fa) || ((fb == fa) && (b < a));
      int die  = bd ? a : b;
      int keepr= bd ? b : a;
      // atomic read: me was written by L2 atomics; plain load may hit stale L1 in solo mode
      unsigned long long cur_me = atomicMax(&me[die], 0ULL);
      if (cur_me == val){
        life[die] = w - (bd ? fa : fb);
        lbl[die] = (unsigned)keepr;
      }
    }
    if (solo) __syncthreads(); else grid.sync();

    p ^= 1; n_prev = n_new;
    if (++roundIdx >= MAXR) break;      // safety cap
  }

  // ---- top-5 lifetimes -> per-image loss (leader block only) ----
  float t5[5] = {-1.f,-1.f,-1.f,-1.f,-1.f};
  for (int i = tid; i < NPIX; i += TPB){
    float v = life[i];
    if (v > t5[4]){
      int j = 4;
      while (j > 0 && t5[j-1] < v){ t5[j] = t5[j-1]; --j; }
      t5[j] = v;
    }
  }
  #pragma unroll
  for (int k = 0; k < 5; ++k) cand[tid*5+k] = t5[k];
  __syncthreads();

  float lsum = 0.0f;
  for (int k = 0; k < 5; ++k){
    float bv = -1.0f; int bi = 0;
    #pragma unroll
    for (int j = 0; j < 5; ++j){
      float v = cand[tid*5+j];
      if (v > bv){ bv = v; bi = tid*5+j; }
    }
    s_val[tid] = bv; s_idx[tid] = bi;
    __syncthreads();
    for (int off = TPB>>1; off > 0; off >>= 1){
      if (tid < off && s_val[tid+off] > s_val[tid]){
        s_val[tid] = s_val[tid+off]; s_idx[tid] = s_idx[tid+off];
      }
      __syncthreads();
    }
    float win = s_val[0];
    if (tid == 0) cand[s_idx[0]] = -2.0f;   // exclude winner slot
    float d = win - 0.5f;                    // TARGET_LIFETIME
    lsum += d*d;
    __syncthreads();
  }
  if (tid == 0) LOSS[img] = lsum * 0.2f;     // / n_use (=5 always; 65535 valid pairs)
}

__global__ void finalize_kernel(const float* __restrict__ LOSS, float* __restrict__ out){
  out[0] = (LOSS[0]+LOSS[1]+LOSS[2]+LOSS[3]) * 25.0f;   // mean * LOSS_SCALE
}

extern "C" void kernel_launch(void* const* d_in, const int* in_sizes, int n_in,
                              void* d_out, int out_size, void* d_ws, size_t ws_size,
                              hipStream_t stream)
{
  const float* prob = (const float*)d_in[0];
  const float* roi  = (const float*)d_in[1];
  char* ws = (char*)d_ws;
  // layout: F 1MB | LIFE 1MB | LBL 1MB | ME 2MB | LA 4.18MB | LB 4.18MB | C 32B | LOSS
  float*              F    = (float*)ws;
  float*              LIFE = (float*)(ws + (1<<20));
  unsigned int*       LBL  = (unsigned int*)(ws + (2<<20));
  unsigned long long* ME   = (unsigned long long*)(ws + (3<<20));
  unsigned long long* LA   = (unsigned long long*)(ws + (5<<20));
  unsigned long long* LB   = (unsigned long long*)(ws + (5<<20) + (size_t)4*NE*8);
  unsigned int*       C    = (unsigned int*)(ws + (5<<20) + (size_t)8*NE*8);
  float*              LOSS = (float*)(ws + (5<<20) + (size_t)8*NE*8 + 64);

  void* args[] = { (void*)&prob, (void*)&roi, (void*)&F, (void*)&LIFE, (void*)&LBL,
                   (void*)&ME, (void*)&LA, (void*)&LB, (void*)&C, (void*)&LOSS };
  hipLaunchCooperativeKernel((void*)ph0_coop, dim3(NBLK), dim3(TPB), args, 0, stream);
  finalize_kernel<<<1, 1, 0, stream>>>(LOSS, (float*)d_out);
}